// Round 2
// baseline (474.752 us; speedup 1.0000x reference)
//
#include <hip/hip_runtime.h>

// DCT_Layer: fixed 4x4 separable 2D-DCT grouped conv, padding=2, min(|out|,8).
// x: (8,3,512,512) fp32 -> out: (8,48,513,513) fp32
//
// R2 structure: block = one output row (oh) x 256 ow x one (b,c).
// Each thread computes the VERTICAL butterfly for its column ONCE (4 loads,
// 14 VALU), publishes float4{t0..t3} to LDS; horizontal butterfly then reads
// the 4-column window (3 LDS reads + own regs). This kills the 4x vertical
// redundancy and all per-lane border predication (oh is block-uniform).
// Clamp = v_min_f32 with free |x| modifier. Stores: uniform-base + 32-bit
// unsigned offsets (out < 4GB) -> saddr-form global_store, 1 v_add each.
// ow=512 edge column handled by a tiny second kernel to keep lane<->ow
// coalescing perfect in the main kernel.

#define IW 512
#define PLANE 263169u  // 513*513

__device__ __forceinline__ float4 vtrans(const float* __restrict__ xin,
                                         int c, int ih0) {
    const float A1 = 0.6532814824381883f;   // sqrt(.5)*cos(pi/8)
    const float A2 = 0.2705980500730985f;   // sqrt(.5)*cos(3pi/8)
    float p0 = 0.f, p1 = 0.f, p2 = 0.f, p3 = 0.f;
    if ((unsigned)c < (unsigned)IW) {
        const float* col = xin + c;
        if ((unsigned)(ih0 + 0) < (unsigned)IW) p0 = col[(ih0 + 0) * IW];
        if ((unsigned)(ih0 + 1) < (unsigned)IW) p1 = col[(ih0 + 1) * IW];
        if ((unsigned)(ih0 + 2) < (unsigned)IW) p2 = col[(ih0 + 2) * IW];
        if ((unsigned)(ih0 + 3) < (unsigned)IW) p3 = col[(ih0 + 3) * IW];
    }
    float s03 = p0 + p3, d03 = p0 - p3, s12 = p1 + p2, d12 = p1 - p2;
    return make_float4(0.5f * (s03 + s12), A1 * d03 + A2 * d12,
                       0.5f * (s03 - s12), A2 * d03 - A1 * d12);
}

__global__ __launch_bounds__(256) void dct_main(const float* __restrict__ x,
                                                float* __restrict__ out) {
    const float A1 = 0.6532814824381883f;
    const float A2 = 0.2705980500730985f;
    __shared__ float4 tc[259];          // vertical-transformed cols, +halo

    int tid  = threadIdx.x;
    int base = blockIdx.x << 8;         // 0 or 256
    int oh   = blockIdx.y;              // 0..512 (uniform per block)
    int bc   = blockIdx.z;              // 0..23
    const float* xin = x + (size_t)bc * (IW * IW);
    int ih0 = oh - 2;

    // own column: col = base + tid -> LDS index tid+2
    float4 own = vtrans(xin, base + tid, ih0);
    tc[tid + 2] = own;
    // halo columns: base-2, base-1 (idx 0,1) and base+256 (idx 258)
    if (tid < 3) {
        int idx = (tid < 2) ? tid : 258;
        int c   = (tid < 2) ? (base - 2 + tid) : (base + 256);
        tc[idx] = vtrans(xin, c, ih0);
    }
    __syncthreads();

    float4 t0 = tc[tid];                // col ow-2
    float4 t1 = tc[tid + 1];            // col ow-1
    float4 t3 = tc[tid + 3];            // col ow+1  (own == col ow)

    unsigned obase = (unsigned)bc * (16u * PLANE) + (unsigned)oh * 513u
                   + (unsigned)(base + tid);

    float c0[4] = {t0.x, t0.y, t0.z, t0.w};
    float c1[4] = {t1.x, t1.y, t1.z, t1.w};
    float c2[4] = {own.x, own.y, own.z, own.w};
    float c3[4] = {t3.x, t3.y, t3.z, t3.w};

#pragma unroll
    for (int m = 0; m < 4; ++m) {
        float s03 = c0[m] + c3[m], d03 = c0[m] - c3[m];
        float s12 = c1[m] + c2[m], d12 = c1[m] - c2[m];
        float r0 = 0.5f * (s03 + s12);
        float r1 = A1 * d03 + A2 * d12;
        float r2 = 0.5f * (s03 - s12);
        float r3 = A2 * d03 - A1 * d12;
        out[obase + (unsigned)(m * 4 + 0) * PLANE] = fminf(fabsf(r0), 8.0f);
        out[obase + (unsigned)(m * 4 + 1) * PLANE] = fminf(fabsf(r1), 8.0f);
        out[obase + (unsigned)(m * 4 + 2) * PLANE] = fminf(fabsf(r2), 8.0f);
        out[obase + (unsigned)(m * 4 + 3) * PLANE] = fminf(fabsf(r3), 8.0f);
    }
}

// ow = 512 edge column: one thread per (bc, oh). Window cols 510..513, only
// 510/511 valid -> t2 = t3 = 0 in the horizontal butterfly.
__global__ __launch_bounds__(256) void dct_edge(const float* __restrict__ x,
                                                float* __restrict__ out) {
    const float A1 = 0.6532814824381883f;
    const float A2 = 0.2705980500730985f;
    int g = blockIdx.x * 256 + threadIdx.x;   // bc*513 + oh
    if (g >= 24 * 513) return;
    int bc = g / 513;
    int oh = g - bc * 513;
    const float* xin = x + (size_t)bc * (IW * IW);
    int ih0 = oh - 2;

    float4 t0 = vtrans(xin, 510, ih0);
    float4 t1 = vtrans(xin, 511, ih0);
    float c0[4] = {t0.x, t0.y, t0.z, t0.w};
    float c1[4] = {t1.x, t1.y, t1.z, t1.w};

    unsigned obase = (unsigned)bc * (16u * PLANE) + (unsigned)oh * 513u + 512u;
#pragma unroll
    for (int m = 0; m < 4; ++m) {
        float s03 = c0[m], d03 = c0[m];         // c3 = 0
        float s12 = c1[m], d12 = c1[m];         // c2 = 0
        float r0 = 0.5f * (s03 + s12);
        float r1 = A1 * d03 + A2 * d12;
        float r2 = 0.5f * (s03 - s12);
        float r3 = A2 * d03 - A1 * d12;
        out[obase + (unsigned)(m * 4 + 0) * PLANE] = fminf(fabsf(r0), 8.0f);
        out[obase + (unsigned)(m * 4 + 1) * PLANE] = fminf(fabsf(r1), 8.0f);
        out[obase + (unsigned)(m * 4 + 2) * PLANE] = fminf(fabsf(r2), 8.0f);
        out[obase + (unsigned)(m * 4 + 3) * PLANE] = fminf(fabsf(r3), 8.0f);
    }
}

extern "C" void kernel_launch(void* const* d_in, const int* in_sizes, int n_in,
                              void* d_out, int out_size, void* d_ws, size_t ws_size,
                              hipStream_t stream) {
    const float* x = (const float*)d_in[0];
    float* out = (float*)d_out;
    dim3 grid(2, 513, 24);
    hipLaunchKernelGGL(dct_main, grid, dim3(256), 0, stream, x, out);
    int edge_threads = 24 * 513;
    hipLaunchKernelGGL(dct_edge, dim3((edge_threads + 255) / 256), dim3(256), 0,
                       stream, x, out);
}